// Round 3
// baseline (1549.000 us; speedup 1.0000x reference)
//
#include <hip/hip_runtime.h>

typedef __attribute__((ext_vector_type(8))) __bf16 bf16x8;
typedef __attribute__((ext_vector_type(4))) __bf16 bf16x4;
typedef __attribute__((ext_vector_type(4))) float f32x4;
typedef __attribute__((ext_vector_type(8))) unsigned short u16x8;

static __device__ __forceinline__ unsigned short f2bf(float x) {
    __bf16 h = (__bf16)x;
    return __builtin_bit_cast(unsigned short, h);
}

// ---------------------------------------------------------------- copy x -> h
__global__ __launch_bounds__(256) void copy_f32(const float* __restrict__ x,
                                                float* __restrict__ h, int n) {
    int i = blockIdx.x * 256 + threadIdx.x;
    if (i < n) h[i] = x[i];
}

// ---------------------------------------------------------------- fused weight transpose+cast
// All 4 weights of one layer in one dispatch. 64x64 tiles, float4 loads,
// XOR-swizzled LDS (write: 2-way max, read: conflict-free), bf16x4 stores.
// in fp32 [K,N] -> out bf16 [N,K].
__global__ __launch_bounds__(256) void transpose_all(const float* __restrict__ Wqkv,
                                                     const float* __restrict__ Wo,
                                                     const float* __restrict__ W1,
                                                     const float* __restrict__ W2,
                                                     __bf16* __restrict__ wqkvT,
                                                     __bf16* __restrict__ woT,
                                                     __bf16* __restrict__ w1T,
                                                     __bf16* __restrict__ w2T) {
    int bid = blockIdx.x;
    const float* in;
    __bf16* out;
    int K, N, tn, tk;
    if (bid < 768)       { in = Wqkv; out = wqkvT; K = 1024; N = 3072; tn = bid % 48; tk = bid / 48; }
    else if (bid < 1024) { bid -= 768;  in = Wo; out = woT;  K = 1024; N = 1024; tn = bid % 16; tk = bid / 16; }
    else if (bid < 2048) { bid -= 1024; in = W1; out = w1T;  K = 1024; N = 4096; tn = bid % 64; tk = bid / 64; }
    else                 { bid -= 2048; in = W2; out = w2T;  K = 4096; N = 1024; tn = bid % 16; tk = bid / 16; }

    __shared__ __bf16 tile[64][72];
    int tx = threadIdx.x & 15, ty = threadIdx.x >> 4;
    int n0 = tn * 64, k0 = tk * 64;
#pragma unroll
    for (int p = 0; p < 4; ++p) {
        int k = ty + p * 16;
        float4 v = *(const float4*)&in[(size_t)(k0 + k) * N + n0 + tx * 4];
#pragma unroll
        for (int j = 0; j < 4; ++j) {
            int n = tx * 4 + j;
            tile[n][k ^ (((n >> 2) & 7) << 3)] = (__bf16)((&v.x)[j]);
        }
    }
    __syncthreads();
#pragma unroll
    for (int p = 0; p < 4; ++p) {
        int n = ty + p * 16;
        int ks = (tx * 4) ^ (((n >> 2) & 7) << 3);
        bf16x4 o4;
        o4[0] = tile[n][ks + 0];
        o4[1] = tile[n][ks + 1];
        o4[2] = tile[n][ks + 2];
        o4[3] = tile[n][ks + 3];
        *(bf16x4*)&out[(size_t)(n0 + n) * K + k0 + tx * 4] = o4;
    }
}

// ---------------------------------------------------------------- LayerNorm (1024-wide rows)
template <typename T>
__global__ __launch_bounds__(256) void ln_kernel(const float* __restrict__ in,
                                                 const float* __restrict__ w,
                                                 const float* __restrict__ b,
                                                 T* __restrict__ out) {
    int row = blockIdx.x, tid = threadIdx.x;
    const float* x = in + (size_t)row * 1024;
    float v[4], s = 0.f, ss = 0.f;
#pragma unroll
    for (int i = 0; i < 4; i++) {
        v[i] = x[tid + i * 256];
        s += v[i];
        ss += v[i] * v[i];
    }
#pragma unroll
    for (int off = 32; off >= 1; off >>= 1) {
        s  += __shfl_xor(s, off, 64);
        ss += __shfl_xor(ss, off, 64);
    }
    __shared__ float ps[4], pss[4];
    int wid = tid >> 6, lane = tid & 63;
    if (lane == 0) { ps[wid] = s; pss[wid] = ss; }
    __syncthreads();
    s  = ps[0] + ps[1] + ps[2] + ps[3];
    ss = pss[0] + pss[1] + pss[2] + pss[3];
    float mean = s * (1.f / 1024.f);
    float var  = ss * (1.f / 1024.f) - mean * mean;
    float rstd = rsqrtf(var + 1e-5f);
    T* y = out + (size_t)row * 1024;
#pragma unroll
    for (int i = 0; i < 4; i++) {
        int c = tid + i * 256;
        y[c] = (T)((v[i] - mean) * rstd * w[c] + b[c]);
    }
}

// ---------------------------------------------------------------- bf16 MFMA GEMM, m97-style
// C[M,N] = epilogue( A[M,K] @ BT[N,K]^T + bias ). BM x 128 tile, BK=64,
// 256 threads = 4 waves in 2x2, each wave (BM/2) x 64 via 16x16x32 MFMA.
// Staging via global_load_lds width=16 into LINEAR LDS. Split-K via
// blockIdx.z; ATOMIC epilogue atomicAdds the partial into Cf (residual),
// z==0 adds bias.
typedef const __attribute__((address_space(1))) char gas_char;
typedef __attribute__((address_space(3))) char las_char;

template <int BM, bool GELU_ACT, bool OUT_BF16, bool ATOMIC>
__global__ __launch_bounds__(256, 2) void gemm_glds(const __bf16* __restrict__ A,
                                                    const __bf16* __restrict__ BT,
                                                    const float* __restrict__ bias,
                                                    float* __restrict__ Cf,
                                                    __bf16* __restrict__ Cb,
                                                    int M, int N, int K, int kchunk) {
    constexpr int MI = BM / 32;  // 16-row m-frags per wave
    __shared__ __align__(16) __bf16 As[BM * 64];   // linear [r][64]
    __shared__ __align__(16) __bf16 Bs[128 * 64];  // linear [n][64]
    const int tid = threadIdx.x;
    const int wave = tid >> 6, lane = tid & 63;
    const int quad = lane >> 4, l16 = lane & 15;
    const int wr = wave >> 1, wc = wave & 1;
    const int row0 = blockIdx.y * BM, col0 = blockIdx.x * 128;
    const int kbeg = blockIdx.z * kchunk, kend = kbeg + kchunk;
    const int wbase = tid & 192;  // wave * 64, wave-uniform

    f32x4 acc[MI][4];
#pragma unroll
    for (int mi = 0; mi < MI; ++mi)
#pragma unroll
        for (int ni = 0; ni < 4; ++ni) acc[mi][ni] = (f32x4)0.f;

    for (int k0 = kbeg; k0 < kend; k0 += 64) {
        __syncthreads();  // prior ds_reads done before restaging
#pragma unroll
        for (int i = 0; i < BM / 32; ++i) {
            int id = i * 256 + tid;           // 16B-segment index
            int r = id >> 3, kc = (id & 7) * 8;
            __builtin_amdgcn_global_load_lds(
                (gas_char*)&A[(size_t)(row0 + r) * K + k0 + kc],
                (las_char*)&As[(size_t)(i * 256 + wbase) * 8], 16, 0, 0);
        }
#pragma unroll
        for (int i = 0; i < 4; ++i) {
            int id = i * 256 + tid;
            int r = id >> 3, kc = (id & 7) * 8;
            __builtin_amdgcn_global_load_lds(
                (gas_char*)&BT[(size_t)(col0 + r) * K + k0 + kc],
                (las_char*)&Bs[(size_t)(i * 256 + wbase) * 8], 16, 0, 0);
        }
        __syncthreads();  // compiler drains vmcnt(0) before barrier
#pragma unroll
        for (int kk = 0; kk < 64; kk += 32) {
            bf16x8 af[MI], bfr[4];
#pragma unroll
            for (int mi = 0; mi < MI; ++mi)
                af[mi] = *(const bf16x8*)&As[(wr * (BM / 2) + mi * 16 + l16) * 64 + kk + quad * 8];
#pragma unroll
            for (int ni = 0; ni < 4; ++ni)
                bfr[ni] = *(const bf16x8*)&Bs[(wc * 64 + ni * 16 + l16) * 64 + kk + quad * 8];
#pragma unroll
            for (int mi = 0; mi < MI; ++mi)
#pragma unroll
                for (int ni = 0; ni < 4; ++ni)
                    acc[mi][ni] = __builtin_amdgcn_mfma_f32_16x16x32_bf16(
                        af[mi], bfr[ni], acc[mi][ni], 0, 0, 0);
        }
    }

#pragma unroll
    for (int mi = 0; mi < MI; ++mi) {
#pragma unroll
        for (int reg = 0; reg < 4; ++reg) {
            int m = row0 + wr * (BM / 2) + mi * 16 + quad * 4 + reg;
#pragma unroll
            for (int ni = 0; ni < 4; ++ni) {
                int n = col0 + wc * 64 + ni * 16 + l16;
                float v = acc[mi][ni][reg];
                if (ATOMIC) {
                    if (blockIdx.z == 0) v += bias[n];
                    atomicAdd(&Cf[(size_t)m * N + n], v);
                } else {
                    v += bias[n];
                    if (GELU_ACT) v = 0.5f * v * (1.f + erff(v * 0.70710678118f));
                    if (OUT_BF16) Cb[(size_t)m * N + n] = (__bf16)v;
                    else          Cf[(size_t)m * N + n] = v;
                }
            }
        }
    }
}

// ---------------------------------------------------------------- MFMA flash attention
// bf16 qkv in [b][s][3072], bf16 o out [b][s][1024]. One 256-thread block
// per (64-q tile, head, batch); 4 waves, each wave owns 16 q rows x 64 k.
// Q/K: swizzled global_load_lds (linear dest, XOR'd source+read: rule #21).
// V: reg-staged transpose into Vs[d][kpos] (packed kpos-pair dwords).
// P: per-wave LDS tile [16][72] via shfl-paired b32 writes.
__global__ __launch_bounds__(256, 4) void attn_mfma_kernel(const __bf16* __restrict__ qkv,
                                                           __bf16* __restrict__ o) {
    const int S = 1024;
    int bx = blockIdx.x, h = blockIdx.y, b = blockIdx.z;
    int qt = (b == 0) ? (15 - bx) : bx;  // balance causal skew
    int tid = threadIdx.x;
    const int wave = tid >> 6, lane = tid & 63;
    const int quad = lane >> 4, l16 = lane & 15;
    const int wbase = tid & 192;

    __shared__ __align__(16) __bf16 Qs[64 * 64];
    __shared__ __align__(16) __bf16 Ks[64 * 64];
    __shared__ __align__(16) unsigned int Vs[64 * 36];  // [d][kpos pairs], stride 36 dw
    __shared__ __align__(16) __bf16 Ps[4][16 * 72];

    const __bf16* base = qkv + (size_t)b * S * 3072 + h * 64;
    const __bf16* qb = base;
    const __bf16* kb = base + 1024;
    const __bf16* vb = base + 2048;
    const int q0 = qt * 64;

    // stage Q once (swizzled)
#pragma unroll
    for (int i = 0; i < 2; ++i) {
        int id = i * 256 + tid, r = id >> 3, cseg = id & 7;
        __builtin_amdgcn_global_load_lds(
            (gas_char*)&qb[(size_t)(q0 + r) * 3072 + ((cseg ^ (r & 7)) << 3)],
            (las_char*)&Qs[(size_t)(i * 256 + wbase) * 8], 16, 0, 0);
    }

    float m_i[4], l_i[4];
    f32x4 acc[4];  // acc[ni][reg] = O[quad*4+reg][ni*16+l16]
#pragma unroll
    for (int r = 0; r < 4; ++r) { m_i[r] = -1e30f; l_i[r] = 0.f; acc[r] = (f32x4)0.f; }

    const int qrow = wave * 16 + quad * 4;  // + reg
    __bf16* Pw = Ps[wave];

    for (int c = 0; c <= qt; ++c) {
        const int k0 = c * 64;
        __syncthreads();  // all waves done reading Ks (QK) / Vs (PV) of prev tile
        // stage K (swizzled glds)
#pragma unroll
        for (int i = 0; i < 2; ++i) {
            int id = i * 256 + tid, r = id >> 3, cseg = id & 7;
            __builtin_amdgcn_global_load_lds(
                (gas_char*)&kb[(size_t)(k0 + r) * 3072 + ((cseg ^ (r & 7)) << 3)],
                (las_char*)&Ks[(size_t)(i * 256 + wbase) * 8], 16, 0, 0);
        }
        // stage V transposed: Vs[d][kpos], two kpos packed per dword
        {
            int pr = tid & 31, d0 = (tid >> 5) << 3;
            u16x8 v0 = *(const u16x8*)&vb[(size_t)(k0 + 2 * pr) * 3072 + d0];
            u16x8 v1 = *(const u16x8*)&vb[(size_t)(k0 + 2 * pr + 1) * 3072 + d0];
#pragma unroll
            for (int j = 0; j < 8; ++j)
                Vs[(d0 + j) * 36 + pr] = (unsigned)v0[j] | ((unsigned)v1[j] << 16);
        }
        __syncthreads();  // drains vmcnt(0): Q (first iter), K, and lgkm for V writes

        // ---- QK^T: S[16 q][64 k] per wave
        f32x4 s4[4];
#pragma unroll
        for (int ni = 0; ni < 4; ++ni) s4[ni] = (f32x4)0.f;
#pragma unroll
        for (int kkk = 0; kkk < 2; ++kkk) {
            int rq = wave * 16 + l16;
            bf16x8 af = *(const bf16x8*)&Qs[rq * 64 + (((kkk * 4 + quad) ^ (rq & 7)) << 3)];
#pragma unroll
            for (int ni = 0; ni < 4; ++ni) {
                int rk = ni * 16 + l16;
                bf16x8 bfr = *(const bf16x8*)&Ks[rk * 64 + (((kkk * 4 + quad) ^ (rk & 7)) << 3)];
                s4[ni] = __builtin_amdgcn_mfma_f32_16x16x32_bf16(af, bfr, s4[ni], 0, 0, 0);
            }
        }

        // ---- online softmax (wave-parallel; rows live in 16-lane groups)
        float p[4][4];
        const bool diag = (c == qt);
#pragma unroll
        for (int reg = 0; reg < 4; ++reg) {
            float mx = -1e30f;
#pragma unroll
            for (int ni = 0; ni < 4; ++ni) {
                float sv = s4[ni][reg] * 0.125f;
                if (diag && (k0 + ni * 16 + l16 > q0 + qrow + reg)) sv = -1e30f;
                p[ni][reg] = sv;
                mx = fmaxf(mx, sv);
            }
#pragma unroll
            for (int off = 8; off >= 1; off >>= 1) mx = fmaxf(mx, __shfl_xor(mx, off, 64));
            float mnew = fmaxf(m_i[reg], mx);
            float alpha = __expf(m_i[reg] - mnew);
            m_i[reg] = mnew;
            float rs = 0.f;
#pragma unroll
            for (int ni = 0; ni < 4; ++ni) {
                float e = __expf(p[ni][reg] - mnew);
                p[ni][reg] = e;
                rs += e;
            }
#pragma unroll
            for (int off = 8; off >= 1; off >>= 1) rs += __shfl_xor(rs, off, 64);
            l_i[reg] = l_i[reg] * alpha + rs;
#pragma unroll
            for (int ni = 0; ni < 4; ++ni) acc[ni][reg] *= alpha;
        }

        // ---- P -> bf16 -> per-wave LDS tile (paired b32 writes, no sub-dword hazard)
#pragma unroll
        for (int reg = 0; reg < 4; ++reg)
#pragma unroll
            for (int ni = 0; ni < 4; ++ni) {
                float pv = p[ni][reg];
                float po = __shfl_xor(pv, 1, 64);
                if ((l16 & 1) == 0) {
                    unsigned u = (unsigned)f2bf(pv) | ((unsigned)f2bf(po) << 16);
                    *(unsigned*)&Pw[(quad * 4 + reg) * 72 + ni * 16 + l16] = u;
                }
            }

        // ---- PV: O[16 q][64 d] += P[16][64] @ V[64][64]
        const __bf16* Vb = (const __bf16*)Vs;
#pragma unroll
        for (int kkk = 0; kkk < 2; ++kkk) {
            bf16x8 af = *(const bf16x8*)&Pw[l16 * 72 + kkk * 32 + quad * 8];
#pragma unroll
            for (int ni = 0; ni < 4; ++ni) {
                bf16x8 bfr = *(const bf16x8*)&Vb[(ni * 16 + l16) * 72 + kkk * 32 + quad * 8];
                acc[ni] = __builtin_amdgcn_mfma_f32_16x16x32_bf16(af, bfr, acc[ni], 0, 0, 0);
            }
        }
    }

    // ---- epilogue: O / l
#pragma unroll
    for (int reg = 0; reg < 4; ++reg) {
        float inv = 1.f / l_i[reg];
        int q = q0 + qrow + reg;
#pragma unroll
        for (int ni = 0; ni < 4; ++ni)
            o[((size_t)b * S + q) * 1024 + h * 64 + ni * 16 + l16] =
                (__bf16)(acc[ni][reg] * inv);
    }
}

// ---------------------------------------------------------------- final projection to WIN=5
__global__ __launch_bounds__(64) void proj_kernel(const float* __restrict__ hn,
                                                  const float* __restrict__ Wp,
                                                  const float* __restrict__ bp,
                                                  float* __restrict__ out) {
    int t = blockIdx.x, lane = threadIdx.x;
    const float* x = hn + (size_t)t * 1024;
    float acc[5] = {0.f, 0.f, 0.f, 0.f, 0.f};
    for (int d = lane; d < 1024; d += 64) {
        float xv = x[d];
#pragma unroll
        for (int j = 0; j < 5; j++) acc[j] += xv * Wp[d * 5 + j];
    }
#pragma unroll
    for (int j = 0; j < 5; j++)
#pragma unroll
        for (int off = 32; off >= 1; off >>= 1) acc[j] += __shfl_xor(acc[j], off, 64);
    if (lane == 0) {
#pragma unroll
        for (int j = 0; j < 5; j++)
            out[(size_t)t * 5 + j] = acc[j] + bp[j];
    }
}

// ---------------------------------------------------------------- launch
extern "C" void kernel_launch(void* const* d_in, const int* in_sizes, int n_in,
                              void* d_out, int out_size, void* d_ws, size_t ws_size,
                              hipStream_t stream) {
    const float* x    = (const float*)d_in[0];
    const float* Wqkv = (const float*)d_in[1];
    const float* bqkv = (const float*)d_in[2];
    const float* Wo   = (const float*)d_in[3];
    const float* bo   = (const float*)d_in[4];
    const float* ln1w = (const float*)d_in[5];
    const float* ln1b = (const float*)d_in[6];
    const float* W1   = (const float*)d_in[7];
    const float* b1   = (const float*)d_in[8];
    const float* W2   = (const float*)d_in[9];
    const float* b2   = (const float*)d_in[10];
    const float* ln2w = (const float*)d_in[11];
    const float* ln2b = (const float*)d_in[12];
    const float* lnfw = (const float*)d_in[13];
    const float* lnfb = (const float*)d_in[14];
    const float* Wp   = (const float*)d_in[15];
    const float* bp   = (const float*)d_in[16];
    float* out = (float*)d_out;

    // workspace layout (~81 MB)
    char* p = (char*)d_ws;
    float*  h    = (float*)p;  p += (size_t)2097152 * 4;   // residual stream fp32
    __bf16* hn_b = (__bf16*)p; p += (size_t)2097152 * 2;   // LN output bf16
    float*  qkv  = (float*)p;  p += (size_t)6291456 * 4;   // qkv bf16 region / lnf fp32 out
    __bf16* o_b  = (__bf16*)p; p += (size_t)2097152 * 2;   // attention out bf16
    __bf16* ff_b = (__bf16*)p; p += (size_t)8388608 * 2;   // FFN mid bf16
    __bf16* wT   = (__bf16*)p;                              // per-layer transposed weights
    __bf16* wqkvT = wT;                 // [3072][1024]
    __bf16* woT   = wqkvT + 3145728;    // [1024][1024]
    __bf16* w1T   = woT   + 1048576;    // [4096][1024]
    __bf16* w2T   = w1T   + 4194304;    // [1024][4096]
    __bf16* qkv_b = (__bf16*)qkv;       // bf16 qkv [2][1024][3072]

    copy_f32<<<8192, 256, 0, stream>>>(x, h, 2097152);

    for (int l = 0; l < 6; ++l) {
        transpose_all<<<3072, 256, 0, stream>>>(
            Wqkv + (size_t)l * 3145728, Wo + (size_t)l * 1048576,
            W1 + (size_t)l * 4194304, W2 + (size_t)l * 4194304,
            wqkvT, woT, w1T, w2T);

        ln_kernel<__bf16><<<2048, 256, 0, stream>>>(h, ln1w + l * 1024, ln1b + l * 1024, hn_b);
        // QKV: 2048x3072x1024 -> bf16, 128-tile, 384 blocks
        gemm_glds<128, false, true, false><<<dim3(24, 16, 1), 256, 0, stream>>>(
            hn_b, wqkvT, bqkv + l * 3072, nullptr, qkv_b, 2048, 3072, 1024, 1024);
        attn_mfma_kernel<<<dim3(16, 16, 2), 256, 0, stream>>>(qkv_b, o_b);
        // attn out: 2048x1024x1024, BM=64 split-K=2 -> 512 blocks, atomic += into h
        gemm_glds<64, false, false, true><<<dim3(8, 32, 2), 256, 0, stream>>>(
            o_b, woT, bo + l * 1024, h, nullptr, 2048, 1024, 1024, 512);
        ln_kernel<__bf16><<<2048, 256, 0, stream>>>(h, ln2w + l * 1024, ln2b + l * 1024, hn_b);
        // FFN1: 2048x4096x1024 + GELU, 128-tile, 512 blocks
        gemm_glds<128, true, true, false><<<dim3(32, 16, 1), 256, 0, stream>>>(
            hn_b, w1T, b1 + l * 4096, nullptr, ff_b, 2048, 4096, 1024, 1024);
        // FFN2: 2048x1024x4096, 128-tile split-K=4 -> 512 blocks, atomic += into h
        gemm_glds<128, false, false, true><<<dim3(8, 16, 4), 256, 0, stream>>>(
            ff_b, w2T, b2 + l * 1024, h, nullptr, 2048, 1024, 4096, 1024);
    }
    float* hn_f = qkv;  // reuse qkv buffer for lnf output (fp32)
    ln_kernel<float><<<2048, 256, 0, stream>>>(h, lnfw, lnfb, hn_f);
    proj_kernel<<<2048, 64, 0, stream>>>(hn_f, Wp, bp, out);
}

// Round 4
// 1420.457 us; speedup vs baseline: 1.0905x; 1.0905x over previous
//
#include <hip/hip_runtime.h>

typedef __attribute__((ext_vector_type(8))) __bf16 bf16x8;
typedef __attribute__((ext_vector_type(4))) __bf16 bf16x4;
typedef __attribute__((ext_vector_type(4))) float f32x4;
typedef __attribute__((ext_vector_type(8))) unsigned short u16x8;

static __device__ __forceinline__ unsigned short f2bf(float x) {
    __bf16 h = (__bf16)x;
    return __builtin_bit_cast(unsigned short, h);
}

// ---------------------------------------------------------------- copy x -> h
__global__ __launch_bounds__(256) void copy_f32(const float* __restrict__ x,
                                                float* __restrict__ h, int n) {
    int i = blockIdx.x * 256 + threadIdx.x;
    if (i < n) h[i] = x[i];
}

// ---------------------------------------------------------------- fused weight transpose+cast
// All 4 weights of one layer in one dispatch. 64x64 tiles, float4 loads,
// XOR-swizzled LDS (write: 2-way max, read: conflict-free), bf16x4 stores.
// in fp32 [K,N] -> out bf16 [N,K].
__global__ __launch_bounds__(256) void transpose_all(const float* __restrict__ Wqkv,
                                                     const float* __restrict__ Wo,
                                                     const float* __restrict__ W1,
                                                     const float* __restrict__ W2,
                                                     __bf16* __restrict__ wqkvT,
                                                     __bf16* __restrict__ woT,
                                                     __bf16* __restrict__ w1T,
                                                     __bf16* __restrict__ w2T) {
    int bid = blockIdx.x;
    const float* in;
    __bf16* out;
    int K, N, tn, tk;
    if (bid < 768)       { in = Wqkv; out = wqkvT; K = 1024; N = 3072; tn = bid % 48; tk = bid / 48; }
    else if (bid < 1024) { bid -= 768;  in = Wo; out = woT;  K = 1024; N = 1024; tn = bid % 16; tk = bid / 16; }
    else if (bid < 2048) { bid -= 1024; in = W1; out = w1T;  K = 1024; N = 4096; tn = bid % 64; tk = bid / 64; }
    else                 { bid -= 2048; in = W2; out = w2T;  K = 4096; N = 1024; tn = bid % 16; tk = bid / 16; }

    __shared__ __bf16 tile[64][72];
    int tx = threadIdx.x & 15, ty = threadIdx.x >> 4;
    int n0 = tn * 64, k0 = tk * 64;
#pragma unroll
    for (int p = 0; p < 4; ++p) {
        int k = ty + p * 16;
        float4 v = *(const float4*)&in[(size_t)(k0 + k) * N + n0 + tx * 4];
#pragma unroll
        for (int j = 0; j < 4; ++j) {
            int n = tx * 4 + j;
            tile[n][k ^ (((n >> 2) & 7) << 3)] = (__bf16)((&v.x)[j]);
        }
    }
    __syncthreads();
#pragma unroll
    for (int p = 0; p < 4; ++p) {
        int n = ty + p * 16;
        int ks = (tx * 4) ^ (((n >> 2) & 7) << 3);
        bf16x4 o4;
        o4[0] = tile[n][ks + 0];
        o4[1] = tile[n][ks + 1];
        o4[2] = tile[n][ks + 2];
        o4[3] = tile[n][ks + 3];
        *(bf16x4*)&out[(size_t)(n0 + n) * K + k0 + tx * 4] = o4;
    }
}

// ---------------------------------------------------------------- LayerNorm (1024-wide rows)
template <typename T>
__global__ __launch_bounds__(256) void ln_kernel(const float* __restrict__ in,
                                                 const float* __restrict__ w,
                                                 const float* __restrict__ b,
                                                 T* __restrict__ out) {
    int row = blockIdx.x, tid = threadIdx.x;
    const float* x = in + (size_t)row * 1024;
    float v[4], s = 0.f, ss = 0.f;
#pragma unroll
    for (int i = 0; i < 4; i++) {
        v[i] = x[tid + i * 256];
        s += v[i];
        ss += v[i] * v[i];
    }
#pragma unroll
    for (int off = 32; off >= 1; off >>= 1) {
        s  += __shfl_xor(s, off, 64);
        ss += __shfl_xor(ss, off, 64);
    }
    __shared__ float ps[4], pss[4];
    int wid = tid >> 6, lane = tid & 63;
    if (lane == 0) { ps[wid] = s; pss[wid] = ss; }
    __syncthreads();
    s  = ps[0] + ps[1] + ps[2] + ps[3];
    ss = pss[0] + pss[1] + pss[2] + pss[3];
    float mean = s * (1.f / 1024.f);
    float var  = ss * (1.f / 1024.f) - mean * mean;
    float rstd = rsqrtf(var + 1e-5f);
    T* y = out + (size_t)row * 1024;
#pragma unroll
    for (int i = 0; i < 4; i++) {
        int c = tid + i * 256;
        y[c] = (T)((v[i] - mean) * rstd * w[c] + b[c]);
    }
}

// ---------------------------------------------------------------- bf16 MFMA GEMM
// C[M,N] = epilogue( A[M,K] @ BT[N,K]^T + bias ). BM x BN tile, BK=64,
// 256 threads = 4 waves in 2x2, wave covers (BM/2) x (BN/2) via 16x16x32
// MFMA. Staging via global_load_lds width=16 into LINEAR LDS. Split-K via
// blockIdx.z; ATOMIC epilogue atomicAdds into Cf (residual), z==0 adds bias.
// Small BN=64 variant trades per-block intensity for 2x resident blocks —
// these shapes are latency-bound, not BW-bound (HBM ~20% of peak).
typedef const __attribute__((address_space(1))) char gas_char;
typedef __attribute__((address_space(3))) char las_char;

template <int BM, int BN, bool GELU_ACT, bool OUT_BF16, bool ATOMIC>
__global__ __launch_bounds__(256, 4) void gemm_glds(const __bf16* __restrict__ A,
                                                    const __bf16* __restrict__ BT,
                                                    const float* __restrict__ bias,
                                                    float* __restrict__ Cf,
                                                    __bf16* __restrict__ Cb,
                                                    int M, int N, int K, int kchunk) {
    constexpr int MI = BM / 32;  // 16-row m-frags per wave
    constexpr int NI = BN / 32;  // 16-col n-frags per wave
    __shared__ __align__(16) __bf16 As[BM * 64];   // linear [r][64]
    __shared__ __align__(16) __bf16 Bs[BN * 64];   // linear [n][64]
    const int tid = threadIdx.x;
    const int wave = tid >> 6, lane = tid & 63;
    const int quad = lane >> 4, l16 = lane & 15;
    const int wr = wave >> 1, wc = wave & 1;
    const int row0 = blockIdx.y * BM, col0 = blockIdx.x * BN;
    const int kbeg = blockIdx.z * kchunk, kend = kbeg + kchunk;
    const int wbase = tid & 192;  // wave * 64, wave-uniform

    f32x4 acc[MI][NI];
#pragma unroll
    for (int mi = 0; mi < MI; ++mi)
#pragma unroll
        for (int ni = 0; ni < NI; ++ni) acc[mi][ni] = (f32x4)0.f;

    for (int k0 = kbeg; k0 < kend; k0 += 64) {
        __syncthreads();  // prior ds_reads done before restaging
#pragma unroll
        for (int i = 0; i < BM / 32; ++i) {
            int id = i * 256 + tid;           // 16B-segment index
            int r = id >> 3, kc = (id & 7) * 8;
            __builtin_amdgcn_global_load_lds(
                (gas_char*)&A[(size_t)(row0 + r) * K + k0 + kc],
                (las_char*)&As[(size_t)(i * 256 + wbase) * 8], 16, 0, 0);
        }
#pragma unroll
        for (int i = 0; i < BN / 32; ++i) {
            int id = i * 256 + tid;
            int r = id >> 3, kc = (id & 7) * 8;
            __builtin_amdgcn_global_load_lds(
                (gas_char*)&BT[(size_t)(col0 + r) * K + k0 + kc],
                (las_char*)&Bs[(size_t)(i * 256 + wbase) * 8], 16, 0, 0);
        }
        __syncthreads();  // compiler drains vmcnt(0) before barrier
#pragma unroll
        for (int kk = 0; kk < 64; kk += 32) {
            bf16x8 af[MI], bfr[NI];
#pragma unroll
            for (int mi = 0; mi < MI; ++mi)
                af[mi] = *(const bf16x8*)&As[(wr * (BM / 2) + mi * 16 + l16) * 64 + kk + quad * 8];
#pragma unroll
            for (int ni = 0; ni < NI; ++ni)
                bfr[ni] = *(const bf16x8*)&Bs[(wc * (BN / 2) + ni * 16 + l16) * 64 + kk + quad * 8];
#pragma unroll
            for (int mi = 0; mi < MI; ++mi)
#pragma unroll
                for (int ni = 0; ni < NI; ++ni)
                    acc[mi][ni] = __builtin_amdgcn_mfma_f32_16x16x32_bf16(
                        af[mi], bfr[ni], acc[mi][ni], 0, 0, 0);
        }
    }

#pragma unroll
    for (int mi = 0; mi < MI; ++mi) {
#pragma unroll
        for (int reg = 0; reg < 4; ++reg) {
            int m = row0 + wr * (BM / 2) + mi * 16 + quad * 4 + reg;
#pragma unroll
            for (int ni = 0; ni < NI; ++ni) {
                int n = col0 + wc * (BN / 2) + ni * 16 + l16;
                float v = acc[mi][ni][reg];
                if (ATOMIC) {
                    if (blockIdx.z == 0) v += bias[n];
                    atomicAdd(&Cf[(size_t)m * N + n], v);
                } else {
                    v += bias[n];
                    if (GELU_ACT) v = 0.5f * v * (1.f + erff(v * 0.70710678118f));
                    if (OUT_BF16) Cb[(size_t)m * N + n] = (__bf16)v;
                    else          Cf[(size_t)m * N + n] = v;
                }
            }
        }
    }
}

// ---------------------------------------------------------------- MFMA flash attention
// bf16 qkv in [b][s][3072], bf16 o out [b][s][1024]. One 256-thread block
// per (64-q tile, head, batch); 4 waves, each wave owns 16 q rows x 64 k.
// Q/K: swizzled global_load_lds (linear dest, XOR'd source+read: rule #21).
// V: reg-staged transpose into Vs[d][kpos] (packed kpos-pair dwords).
// P: per-wave LDS tile [16][72] via shfl-paired b32 writes.
__global__ __launch_bounds__(256, 4) void attn_mfma_kernel(const __bf16* __restrict__ qkv,
                                                           __bf16* __restrict__ o) {
    const int S = 1024;
    int bx = blockIdx.x, h = blockIdx.y, b = blockIdx.z;
    int qt = (b == 0) ? (15 - bx) : bx;  // balance causal skew
    int tid = threadIdx.x;
    const int wave = tid >> 6, lane = tid & 63;
    const int quad = lane >> 4, l16 = lane & 15;
    const int wbase = tid & 192;

    __shared__ __align__(16) __bf16 Qs[64 * 64];
    __shared__ __align__(16) __bf16 Ks[64 * 64];
    __shared__ __align__(16) unsigned int Vs[64 * 36];  // [d][kpos pairs], stride 36 dw
    __shared__ __align__(16) __bf16 Ps[4][16 * 72];

    const __bf16* base = qkv + (size_t)b * S * 3072 + h * 64;
    const __bf16* qb = base;
    const __bf16* kb = base + 1024;
    const __bf16* vb = base + 2048;
    const int q0 = qt * 64;

    // stage Q once (swizzled)
#pragma unroll
    for (int i = 0; i < 2; ++i) {
        int id = i * 256 + tid, r = id >> 3, cseg = id & 7;
        __builtin_amdgcn_global_load_lds(
            (gas_char*)&qb[(size_t)(q0 + r) * 3072 + ((cseg ^ (r & 7)) << 3)],
            (las_char*)&Qs[(size_t)(i * 256 + wbase) * 8], 16, 0, 0);
    }

    float m_i[4], l_i[4];
    f32x4 acc[4];  // acc[ni][reg] = O[quad*4+reg][ni*16+l16]
#pragma unroll
    for (int r = 0; r < 4; ++r) { m_i[r] = -1e30f; l_i[r] = 0.f; acc[r] = (f32x4)0.f; }

    const int qrow = wave * 16 + quad * 4;  // + reg
    __bf16* Pw = Ps[wave];

    for (int c = 0; c <= qt; ++c) {
        const int k0 = c * 64;
        __syncthreads();  // all waves done reading Ks (QK) / Vs (PV) of prev tile
        // stage K (swizzled glds)
#pragma unroll
        for (int i = 0; i < 2; ++i) {
            int id = i * 256 + tid, r = id >> 3, cseg = id & 7;
            __builtin_amdgcn_global_load_lds(
                (gas_char*)&kb[(size_t)(k0 + r) * 3072 + ((cseg ^ (r & 7)) << 3)],
                (las_char*)&Ks[(size_t)(i * 256 + wbase) * 8], 16, 0, 0);
        }
        // stage V transposed: Vs[d][kpos], two kpos packed per dword
        {
            int pr = tid & 31, d0 = (tid >> 5) << 3;
            u16x8 v0 = *(const u16x8*)&vb[(size_t)(k0 + 2 * pr) * 3072 + d0];
            u16x8 v1 = *(const u16x8*)&vb[(size_t)(k0 + 2 * pr + 1) * 3072 + d0];
#pragma unroll
            for (int j = 0; j < 8; ++j)
                Vs[(d0 + j) * 36 + pr] = (unsigned)v0[j] | ((unsigned)v1[j] << 16);
        }
        __syncthreads();  // drains vmcnt(0): Q (first iter), K, and lgkm for V writes

        // ---- QK^T: S[16 q][64 k] per wave
        f32x4 s4[4];
#pragma unroll
        for (int ni = 0; ni < 4; ++ni) s4[ni] = (f32x4)0.f;
#pragma unroll
        for (int kkk = 0; kkk < 2; ++kkk) {
            int rq = wave * 16 + l16;
            bf16x8 af = *(const bf16x8*)&Qs[rq * 64 + (((kkk * 4 + quad) ^ (rq & 7)) << 3)];
#pragma unroll
            for (int ni = 0; ni < 4; ++ni) {
                int rk = ni * 16 + l16;
                bf16x8 bfr = *(const bf16x8*)&Ks[rk * 64 + (((kkk * 4 + quad) ^ (rk & 7)) << 3)];
                s4[ni] = __builtin_amdgcn_mfma_f32_16x16x32_bf16(af, bfr, s4[ni], 0, 0, 0);
            }
        }

        // ---- online softmax (wave-parallel; rows live in 16-lane groups)
        float p[4][4];
        const bool diag = (c == qt);
#pragma unroll
        for (int reg = 0; reg < 4; ++reg) {
            float mx = -1e30f;
#pragma unroll
            for (int ni = 0; ni < 4; ++ni) {
                float sv = s4[ni][reg] * 0.125f;
                if (diag && (k0 + ni * 16 + l16 > q0 + qrow + reg)) sv = -1e30f;
                p[ni][reg] = sv;
                mx = fmaxf(mx, sv);
            }
#pragma unroll
            for (int off = 8; off >= 1; off >>= 1) mx = fmaxf(mx, __shfl_xor(mx, off, 64));
            float mnew = fmaxf(m_i[reg], mx);
            float alpha = __expf(m_i[reg] - mnew);
            m_i[reg] = mnew;
            float rs = 0.f;
#pragma unroll
            for (int ni = 0; ni < 4; ++ni) {
                float e = __expf(p[ni][reg] - mnew);
                p[ni][reg] = e;
                rs += e;
            }
#pragma unroll
            for (int off = 8; off >= 1; off >>= 1) rs += __shfl_xor(rs, off, 64);
            l_i[reg] = l_i[reg] * alpha + rs;
#pragma unroll
            for (int ni = 0; ni < 4; ++ni) acc[ni][reg] *= alpha;
        }

        // ---- P -> bf16 -> per-wave LDS tile (paired b32 writes, no sub-dword hazard)
#pragma unroll
        for (int reg = 0; reg < 4; ++reg)
#pragma unroll
            for (int ni = 0; ni < 4; ++ni) {
                float pv = p[ni][reg];
                float po = __shfl_xor(pv, 1, 64);
                if ((l16 & 1) == 0) {
                    unsigned u = (unsigned)f2bf(pv) | ((unsigned)f2bf(po) << 16);
                    *(unsigned*)&Pw[(quad * 4 + reg) * 72 + ni * 16 + l16] = u;
                }
            }

        // ---- PV: O[16 q][64 d] += P[16][64] @ V[64][64]
        const __bf16* Vb = (const __bf16*)Vs;
#pragma unroll
        for (int kkk = 0; kkk < 2; ++kkk) {
            bf16x8 af = *(const bf16x8*)&Pw[l16 * 72 + kkk * 32 + quad * 8];
#pragma unroll
            for (int ni = 0; ni < 4; ++ni) {
                bf16x8 bfr = *(const bf16x8*)&Vb[(ni * 16 + l16) * 72 + kkk * 32 + quad * 8];
                acc[ni] = __builtin_amdgcn_mfma_f32_16x16x32_bf16(af, bfr, acc[ni], 0, 0, 0);
            }
        }
    }

    // ---- epilogue: O / l
#pragma unroll
    for (int reg = 0; reg < 4; ++reg) {
        float inv = 1.f / l_i[reg];
        int q = q0 + qrow + reg;
#pragma unroll
        for (int ni = 0; ni < 4; ++ni)
            o[((size_t)b * S + q) * 1024 + h * 64 + ni * 16 + l16] =
                (__bf16)(acc[ni][reg] * inv);
    }
}

// ---------------------------------------------------------------- final projection to WIN=5
__global__ __launch_bounds__(64) void proj_kernel(const float* __restrict__ hn,
                                                  const float* __restrict__ Wp,
                                                  const float* __restrict__ bp,
                                                  float* __restrict__ out) {
    int t = blockIdx.x, lane = threadIdx.x;
    const float* x = hn + (size_t)t * 1024;
    float acc[5] = {0.f, 0.f, 0.f, 0.f, 0.f};
    for (int d = lane; d < 1024; d += 64) {
        float xv = x[d];
#pragma unroll
        for (int j = 0; j < 5; j++) acc[j] += xv * Wp[d * 5 + j];
    }
#pragma unroll
    for (int j = 0; j < 5; j++)
#pragma unroll
        for (int off = 32; off >= 1; off >>= 1) acc[j] += __shfl_xor(acc[j], off, 64);
    if (lane == 0) {
#pragma unroll
        for (int j = 0; j < 5; j++)
            out[(size_t)t * 5 + j] = acc[j] + bp[j];
    }
}

// ---------------------------------------------------------------- launch
extern "C" void kernel_launch(void* const* d_in, const int* in_sizes, int n_in,
                              void* d_out, int out_size, void* d_ws, size_t ws_size,
                              hipStream_t stream) {
    const float* x    = (const float*)d_in[0];
    const float* Wqkv = (const float*)d_in[1];
    const float* bqkv = (const float*)d_in[2];
    const float* Wo   = (const float*)d_in[3];
    const float* bo   = (const float*)d_in[4];
    const float* ln1w = (const float*)d_in[5];
    const float* ln1b = (const float*)d_in[6];
    const float* W1   = (const float*)d_in[7];
    const float* b1   = (const float*)d_in[8];
    const float* W2   = (const float*)d_in[9];
    const float* b2   = (const float*)d_in[10];
    const float* ln2w = (const float*)d_in[11];
    const float* ln2b = (const float*)d_in[12];
    const float* lnfw = (const float*)d_in[13];
    const float* lnfb = (const float*)d_in[14];
    const float* Wp   = (const float*)d_in[15];
    const float* bp   = (const float*)d_in[16];
    float* out = (float*)d_out;

    // workspace layout (~81 MB)
    char* p = (char*)d_ws;
    float*  h    = (float*)p;  p += (size_t)2097152 * 4;   // residual stream fp32
    __bf16* hn_b = (__bf16*)p; p += (size_t)2097152 * 2;   // LN output bf16
    float*  qkv  = (float*)p;  p += (size_t)6291456 * 4;   // qkv bf16 region / lnf fp32 out
    __bf16* o_b  = (__bf16*)p; p += (size_t)2097152 * 2;   // attention out bf16
    __bf16* ff_b = (__bf16*)p; p += (size_t)8388608 * 2;   // FFN mid bf16
    __bf16* wT   = (__bf16*)p;                              // per-layer transposed weights
    __bf16* wqkvT = wT;                 // [3072][1024]
    __bf16* woT   = wqkvT + 3145728;    // [1024][1024]
    __bf16* w1T   = woT   + 1048576;    // [4096][1024]
    __bf16* w2T   = w1T   + 4194304;    // [1024][4096]
    __bf16* qkv_b = (__bf16*)qkv;       // bf16 qkv [2][1024][3072]

    copy_f32<<<8192, 256, 0, stream>>>(x, h, 2097152);

    for (int l = 0; l < 6; ++l) {
        transpose_all<<<3072, 256, 0, stream>>>(
            Wqkv + (size_t)l * 3145728, Wo + (size_t)l * 1048576,
            W1 + (size_t)l * 4194304, W2 + (size_t)l * 4194304,
            wqkvT, woT, w1T, w2T);

        ln_kernel<__bf16><<<2048, 256, 0, stream>>>(h, ln1w + l * 1024, ln1b + l * 1024, hn_b);
        // QKV: 2048x3072x1024 -> bf16, 64x128 tile, 768 blocks (3/CU)
        gemm_glds<64, 128, false, true, false><<<dim3(24, 32, 1), 256, 0, stream>>>(
            hn_b, wqkvT, bqkv + l * 3072, nullptr, qkv_b, 2048, 3072, 1024, 1024);
        attn_mfma_kernel<<<dim3(16, 16, 2), 256, 0, stream>>>(qkv_b, o_b);
        // attn out: 2048x1024x1024, 64x64 tile split-K=2 -> 1024 blocks (4/CU)
        gemm_glds<64, 64, false, false, true><<<dim3(16, 32, 2), 256, 0, stream>>>(
            o_b, woT, bo + l * 1024, h, nullptr, 2048, 1024, 1024, 512);
        ln_kernel<__bf16><<<2048, 256, 0, stream>>>(h, ln2w + l * 1024, ln2b + l * 1024, hn_b);
        // FFN1: 2048x4096x1024 + GELU, 64x128 tile, 1024 blocks (4/CU)
        gemm_glds<64, 128, true, true, false><<<dim3(32, 32, 1), 256, 0, stream>>>(
            hn_b, w1T, b1 + l * 4096, nullptr, ff_b, 2048, 4096, 1024, 1024);
        // FFN2: 2048x1024x4096, 64x64 tile split-K=4 -> 2048 blocks (8/CU)
        gemm_glds<64, 64, false, false, true><<<dim3(16, 32, 4), 256, 0, stream>>>(
            ff_b, w2T, b2 + l * 1024, h, nullptr, 2048, 1024, 4096, 1024);
    }
    float* hn_f = qkv;  // reuse qkv buffer for lnf output (fp32)
    ln_kernel<float><<<2048, 256, 0, stream>>>(h, lnfw, lnfb, hn_f);
    proj_kernel<<<2048, 64, 0, stream>>>(hn_f, Wp, bp, out);
}